// Round 8
// baseline (1183.885 us; speedup 1.0000x reference)
//
#include <hip/hip_runtime.h>
#include <hip/hip_bf16.h>

#define HH 512
#define IN_F 256
#define OUT_F 128
#define NSTEPS 3
#define NL 3
#define RROWS 32
#define STRIDE 520   // bf16 elements; 1040B pitch (16B-aligned rows)
#define NW 4         // 256 threads; wave grid 1 (rows) x 4 (cols); wave tile 32x128

typedef __attribute__((ext_vector_type(8))) short short8;
typedef __attribute__((ext_vector_type(4))) float f32x4;
typedef unsigned short u16;
typedef unsigned int u32;

static __device__ __forceinline__ float bf2f(u16 v){
  return __uint_as_float(((u32)v) << 16);
}
static __device__ __forceinline__ u16 f2bf(float f){   // RNE bf16
  u32 x = __float_as_uint(f);
  x += 0x7fffu + ((x >> 16) & 1u);
  return (u16)(x >> 16);
}
static __device__ __forceinline__ float fast_tanh(float x){
  float e = __expf(2.0f * x);
  return 1.0f - 2.0f / (e + 1.0f);
}
static __device__ __forceinline__ short8 ld8(const u16* p){
  return *reinterpret_cast<const short8*>(p);
}

// ---------------- prep kernels ----------------

__global__ void prep_convert(const float* __restrict__ Wliq, const float* __restrict__ Win,
                             const float* __restrict__ W1, const float* __restrict__ W2,
                             u16* __restrict__ oliq, u16* __restrict__ owin,
                             u16* __restrict__ ow1, u16* __restrict__ ow2)
{
  int tid = blockIdx.x * blockDim.x + threadIdx.x;
  int nt  = gridDim.x * blockDim.x;
  for (int i = tid; i < NL*HH*HH; i += nt){
    int rem = i % (HH*HH);
    int r = rem / HH, c = rem % HH;
    oliq[i] = f2bf(Wliq[i] + ((r == c) ? 1.0f : 0.0f));   // fold +I: pre = h@(W+I)^T + b
  }
  for (int i = tid; i < HH*IN_F;  i += nt) owin[i] = f2bf(Win[i]);
  for (int i = tid; i < HH*2*HH;  i += nt) ow1[i]  = f2bf(W1[i]);
  for (int i = tid; i < OUT_F*HH; i += nt) ow2[i]  = f2bf(W2[i]);
}

// Wovi = W_o @ W_v + I  (so att + liq = Sum_l LN_l @ Wovi^T + b_ov); b_ov = W_o@b_v + b_o
__global__ void prep_ov(const float* __restrict__ Wv, const float* __restrict__ Wo,
                        const float* __restrict__ bv, const float* __restrict__ bo,
                        u16* __restrict__ oov, float* __restrict__ obov)
{
  __shared__ float srow[HH];
  __shared__ float rbuf[256];
  const int i = blockIdx.x;
  const int t = threadIdx.x;
  srow[t]       = Wo[i*HH + t];
  srow[t + 256] = Wo[i*HH + t + 256];
  __syncthreads();
  #pragma unroll
  for (int half = 0; half < 2; ++half){
    int j = t + half*256;
    float a0 = 0.f, a1 = 0.f;
    for (int k = 0; k < HH; k += 2){
      a0 += srow[k]   * Wv[(k)*HH + j];
      a1 += srow[k+1] * Wv[(k+1)*HH + j];
    }
    oov[i*HH + j] = f2bf(a0 + a1 + ((i == j) ? 1.0f : 0.0f));  // +I fold
  }
  float p = 0.f;
  for (int k = t; k < HH; k += 256) p += srow[k] * bv[k];
  rbuf[t] = p; __syncthreads();
  for (int s = 128; s > 0; s >>= 1){ if (t < s) rbuf[t] += rbuf[t + s]; __syncthreads(); }
  if (t == 0) obov[i] = rbuf[0] + bo[i];
}

// Step-0 collapse: h=0 -> pre_l = b_liq[l] -> LN_l = beta_liq[l] exactly.
// c1 = sum_l beta_liq[l]; v = c1@Wovi^T + bov (Wovi has +I so the +c1 is included);
// z = LN(v)*g_att + be_att. Then h1 = tanh(z + xin)/(tau+eps), elementwise.
__global__ void prep_z(const float* __restrict__ be_liq, const float* __restrict__ g_att,
                       const float* __restrict__ be_att, const u16* __restrict__ Wov,
                       const float* __restrict__ bov, float* __restrict__ z_out)
{
  __shared__ float c1s[HH];
  __shared__ float2 rr[HH];
  const int n = threadIdx.x;
  const float c1 = be_liq[n] + be_liq[HH + n] + be_liq[2*HH + n];
  c1s[n] = c1;
  __syncthreads();
  float a = 0.f;
  for (int k = 0; k < HH; ++k) a += c1s[k] * bf2f(Wov[(size_t)n*HH + k]);
  const float v = a + bov[n];   // +c1 already inside (I fold)
  rr[n] = make_float2(v, v*v);
  __syncthreads();
  for (int s = 256; s > 0; s >>= 1){
    if (n < s){ rr[n].x += rr[n+s].x; rr[n].y += rr[n+s].y; }
    __syncthreads();
  }
  const float mu = rr[0].x * (1.f/HH);
  const float va = rr[0].y * (1.f/HH) - mu*mu;
  z_out[n] = (v - mu) * rsqrtf(va + 1e-5f) * g_att[n] + be_att[n];
}

// ---------------- main fused kernel ----------------

#define ZERO28(A) { _Pragma("unroll") for (int _i=0;_i<2;++_i) _Pragma("unroll") for (int _j=0;_j<8;++_j) A[_i][_j] = (f32x4){0.f,0.f,0.f,0.f}; }

__device__ __forceinline__ void gemm32(const u16* ldsA, const u16* __restrict__ W,
    const int Wk, const int kSteps, const int wid, const int lr, const int lg,
    f32x4 (&acc)[2][8])
{
  const u16* pw = W + (size_t)(wid*128 + lr)*Wk + lg*8;
  const u16* pa = ldsA + lr*STRIDE + lg*8;
  #pragma unroll 2
  for (int ks = 0; ks < kSteps; ++ks){
    short8 a0 = ld8(pa + ks*32);
    short8 a1 = ld8(pa + 16*STRIDE + ks*32);
    #pragma unroll
    for (int tn = 0; tn < 8; ++tn){
      short8 b = ld8(pw + (size_t)tn*16*Wk + ks*32);
      acc[0][tn] = __builtin_amdgcn_mfma_f32_16x16x32_bf16(a0, b, acc[0][tn], 0, 0, 0);
      acc[1][tn] = __builtin_amdgcn_mfma_f32_16x16x32_bf16(a1, b, acc[1][tn], 0, 0, 0);
    }
  }
}

// per-row LN stats over 512 cols; results land in red2[row] = (mean, rstd)
__device__ __forceinline__ void ln_rows32(const f32x4 (&v)[2][8],
    const int wid, const int lr, const int lg, const int tid,
    float2* __restrict__ red1, float2* __restrict__ red2)
{
  float s[2][4], q[2][4];
  #pragma unroll
  for (int ti = 0; ti < 2; ++ti)
    #pragma unroll
    for (int r = 0; r < 4; ++r){
      float ss = 0.f, qq = 0.f;
      #pragma unroll
      for (int tn = 0; tn < 8; ++tn){ float xv = v[ti][tn][r]; ss += xv; qq += xv*xv; }
      s[ti][r] = ss; q[ti][r] = qq;
    }
  #pragma unroll
  for (int m = 1; m < 16; m <<= 1)
    #pragma unroll
    for (int ti = 0; ti < 2; ++ti)
      #pragma unroll
      for (int r = 0; r < 4; ++r){
        s[ti][r] += __shfl_xor(s[ti][r], m, 64);
        q[ti][r] += __shfl_xor(q[ti][r], m, 64);
      }
  #pragma unroll
  for (int ti = 0; ti < 2; ++ti)
    #pragma unroll
    for (int r = 0; r < 4; ++r)
      if (lr == ti*4 + r)
        red1[(ti*16 + lg*4 + r)*NW + wid] = make_float2(s[ti][r], q[ti][r]);
  __syncthreads();
  if (tid < RROWS){
    float S = 0.f, Q = 0.f;
    #pragma unroll
    for (int w = 0; w < NW; ++w){ float2 p = red1[tid*NW + w]; S += p.x; Q += p.y; }
    float mu = S * (1.0f/HH);
    float va = Q * (1.0f/HH) - mu*mu;
    red2[tid] = make_float2(mu, rsqrtf(va + 1e-5f));
  }
  __syncthreads();
}

__global__ __launch_bounds__(256) __attribute__((amdgpu_waves_per_eu(2)))
void liquid_main(
    const float* __restrict__ x, const float* __restrict__ b_in,
    const float* __restrict__ b_liq, const float* __restrict__ g_liq, const float* __restrict__ be_liq,
    const float* __restrict__ g_att, const float* __restrict__ be_att,
    const float* __restrict__ tau,
    const float* __restrict__ b1, const float* __restrict__ b2,
    const u16* __restrict__ Wliq_b, const u16* __restrict__ Wovi_b, const float* __restrict__ bov,
    const u16* __restrict__ Win_b, const u16* __restrict__ W1_b, const u16* __restrict__ W2_b,
    const float* __restrict__ zv,
    float* __restrict__ out)
{
  extern __shared__ char smem[];
  u16* A0 = (u16*)smem;                        // h buffer (persists through each step)
  u16* L0 = A0 + RROWS*STRIDE;                 // LN_l operand / h0 buffer
  float2* red1 = (float2*)(L0 + RROWS*STRIDE); // [32][NW]
  float2* red2 = red1 + RROWS*NW;              // [32]

  const int tid = threadIdx.x;
  const int lane = tid & 63;
  const int wid = tid >> 6;      // wave 0..3 (col group)
  const int lr = lane & 15, lg = lane >> 4;
  const int rb = blockIdx.x;

  f32x4 accA[2][8];   // per-GEMM result
  f32x4 accB[2][8];   // pre2 accumulator: Sum_l LN_l @ (Wov+I)^T
  u32 xpk[2][8][2];

  // ---- phase 0: stage x (bf16) into A0 cols 0..255 ----
  {
    const float4* xg = reinterpret_cast<const float4*>(x + (size_t)rb * RROWS * IN_F);
    #pragma unroll
    for (int j = 0; j < 8; ++j){
      int i4 = tid + j*256;
      float4 v = xg[i4];
      int m = i4 >> 6, c = (i4 & 63) << 2;
      u32 lo = (u32)f2bf(v.x) | ((u32)f2bf(v.y) << 16);
      u32 hi = (u32)f2bf(v.z) | ((u32)f2bf(v.w) << 16);
      *reinterpret_cast<uint2*>(A0 + m*STRIDE + c) = make_uint2(lo, hi);
    }
  }
  __syncthreads();
  ZERO28(accA);
  gemm32(A0, Win_b, IN_F, IN_F/32, wid, lr, lg, accA);
  __syncthreads();   // all x-reads of A0 done before h overwrites it

  // xin = x@Win^T + b_in (packed bf16); h1 = tanh(z + xin)*it -> A0
  #pragma unroll
  for (int tn = 0; tn < 8; ++tn){
    const int n = wid*128 + tn*16 + lr;
    const float bi = b_in[n];
    const float zn = zv[n];
    const float it = 1.0f/(tau[n] + 1e-6f);
    #pragma unroll
    for (int ti = 0; ti < 2; ++ti){
      float x0 = accA[ti][tn][0]+bi, x1 = accA[ti][tn][1]+bi;
      float x2 = accA[ti][tn][2]+bi, x3 = accA[ti][tn][3]+bi;
      xpk[ti][tn][0] = (u32)f2bf(x0) | ((u32)f2bf(x1) << 16);
      xpk[ti][tn][1] = (u32)f2bf(x2) | ((u32)f2bf(x3) << 16);
      const int mrow = ti*16 + lg*4;
      A0[(mrow + 0)*STRIDE + n] = f2bf(fast_tanh(zn + x0) * it);
      A0[(mrow + 1)*STRIDE + n] = f2bf(fast_tanh(zn + x1) * it);
      A0[(mrow + 2)*STRIDE + n] = f2bf(fast_tanh(zn + x2) * it);
      A0[(mrow + 3)*STRIDE + n] = f2bf(fast_tanh(zn + x3) * it);
    }
  }

  // ---- steps 1..2 (step 0 collapsed into z) ----
  for (int t = 0; t < NSTEPS-1; ++t){
    __syncthreads();   // h writes visible
    ZERO28(accB);
    for (int l = 0; l < NL; ++l){
      ZERO28(accA);
      gemm32(A0, Wliq_b + (size_t)l*HH*HH, HH, HH/32, wid, lr, lg, accA);
      #pragma unroll
      for (int tn = 0; tn < 8; ++tn){
        const float bb = b_liq[l*HH + wid*128 + tn*16 + lr];
        #pragma unroll
        for (int ti = 0; ti < 2; ++ti)
          #pragma unroll
          for (int r = 0; r < 4; ++r) accA[ti][tn][r] += bb;
      }
      ln_rows32(accA, wid, lr, lg, tid, red1, red2);
      // LN_l -> L0 (bf16)
      #pragma unroll
      for (int tn = 0; tn < 8; ++tn){
        const int n = wid*128 + tn*16 + lr;
        const float gg = g_liq[l*HH + n], be = be_liq[l*HH + n];
        #pragma unroll
        for (int ti = 0; ti < 2; ++ti)
          #pragma unroll
          for (int r = 0; r < 4; ++r){
            const float2 st = red2[ti*16 + lg*4 + r];
            L0[(ti*16 + lg*4 + r)*STRIDE + n] =
                f2bf((accA[ti][tn][r] - st.x) * st.y * gg + be);
          }
      }
      __syncthreads();   // L0 ready
      gemm32(L0, Wovi_b, HH, HH/32, wid, lr, lg, accB);  // accB += LN_l @ (Wov+I)^T
      __syncthreads();   // L0 reads done before next l overwrites
    }
    // + b_ov; LN2; h update
    #pragma unroll
    for (int tn = 0; tn < 8; ++tn){
      const float bo_ = bov[wid*128 + tn*16 + lr];
      #pragma unroll
      for (int ti = 0; ti < 2; ++ti)
        #pragma unroll
        for (int r = 0; r < 4; ++r) accB[ti][tn][r] += bo_;
    }
    ln_rows32(accB, wid, lr, lg, tid, red1, red2);
    #pragma unroll
    for (int tn = 0; tn < 8; ++tn){
      const int n = wid*128 + tn*16 + lr;
      const float ga = g_att[n], ba = be_att[n];
      const float it = 1.0f/(tau[n] + 1e-6f);
      #pragma unroll
      for (int ti = 0; ti < 2; ++ti)
        #pragma unroll
        for (int r = 0; r < 4; ++r){
          const int m = ti*16 + lg*4 + r;
          const float2 st = red2[m];
          const float l2 = (accB[ti][tn][r] - st.x) * st.y * ga + ba;
          const float xi = bf2f((u16)(xpk[ti][tn][r >> 1] >> ((r & 1) * 16)));
          const float ho = bf2f(A0[m*STRIDE + n]);
          A0[m*STRIDE + n] = f2bf(ho + (fast_tanh(l2 + xi) - ho) * it);
        }
    }
  }

  // ---- head: h0 = tanh(z+xin)*it -> L0 (recomputed from xpk) ----
  #pragma unroll
  for (int tn = 0; tn < 8; ++tn){
    const int n = wid*128 + tn*16 + lr;
    const float zn = zv[n];
    const float it = 1.0f/(tau[n] + 1e-6f);
    #pragma unroll
    for (int ti = 0; ti < 2; ++ti)
      #pragma unroll
      for (int r = 0; r < 4; ++r){
        const float xi = bf2f((u16)(xpk[ti][tn][r >> 1] >> ((r & 1) * 16)));
        L0[(ti*16 + lg*4 + r)*STRIDE + n] = f2bf(fast_tanh(zn + xi) * it);
      }
  }
  __syncthreads();   // h (A0) + h0 (L0) ready
  ZERO28(accA);
  gemm32(A0, W1_b,      2*HH, HH/32, wid, lr, lg, accA);  // h part (k 0..511)
  gemm32(L0, W1_b + HH, 2*HH, HH/32, wid, lr, lg, accA);  // h0 part (k 512..1023)
  #pragma unroll
  for (int tn = 0; tn < 8; ++tn){
    const float bb = b1[wid*128 + tn*16 + lr];
    #pragma unroll
    for (int ti = 0; ti < 2; ++ti)
      #pragma unroll
      for (int r = 0; r < 4; ++r)
        accA[ti][tn][r] = fmaxf(accA[ti][tn][r] + bb, 0.f);
  }
  __syncthreads();   // W1 gemm reads of A0 done before overwrite
  #pragma unroll
  for (int ti = 0; ti < 2; ++ti)
    #pragma unroll
    for (int tn = 0; tn < 8; ++tn){
      const int n = wid*128 + tn*16 + lr;
      #pragma unroll
      for (int r = 0; r < 4; ++r)
        A0[(ti*16 + lg*4 + r)*STRIDE + n] = f2bf(accA[ti][tn][r]);
    }
  __syncthreads();

  // final [32,512] @ W2^T -> [32,128]; 4 waves: 32 rows x 32 cols per wave
  {
    f32x4 a2[2][2];
    #pragma unroll
    for (int ti = 0; ti < 2; ++ti)
      #pragma unroll
      for (int tn = 0; tn < 2; ++tn) a2[ti][tn] = (f32x4){0.f,0.f,0.f,0.f};
    const u16* pw2 = W2_b + (size_t)(wid*32 + lr)*HH + lg*8;
    const u16* pa2 = A0 + lr*STRIDE + lg*8;
    #pragma unroll 2
    for (int ks = 0; ks < HH/32; ++ks){
      short8 aa0 = ld8(pa2 + ks*32);
      short8 aa1 = ld8(pa2 + 16*STRIDE + ks*32);
      #pragma unroll
      for (int tn = 0; tn < 2; ++tn){
        short8 bb2 = ld8(pw2 + (size_t)tn*16*HH + ks*32);
        a2[0][tn] = __builtin_amdgcn_mfma_f32_16x16x32_bf16(aa0, bb2, a2[0][tn], 0, 0, 0);
        a2[1][tn] = __builtin_amdgcn_mfma_f32_16x16x32_bf16(aa1, bb2, a2[1][tn], 0, 0, 0);
      }
    }
    #pragma unroll
    for (int tn = 0; tn < 2; ++tn){
      const int n = wid*32 + tn*16 + lr;
      const float bb = b2[n];
      #pragma unroll
      for (int ti = 0; ti < 2; ++ti)
        #pragma unroll
        for (int r = 0; r < 4; ++r){
          const int m = ti*16 + lg*4 + r;
          out[(size_t)(rb*RROWS + m)*OUT_F + n] = a2[ti][tn][r] + bb;
        }
    }
  }
}

// ---------------- launch ----------------

extern "C" void kernel_launch(void* const* d_in, const int* in_sizes, int n_in,
                              void* d_out, int out_size, void* d_ws, size_t ws_size,
                              hipStream_t stream)
{
  (void)in_sizes; (void)n_in; (void)out_size; (void)ws_size;
  const float* x      = (const float*)d_in[0];
  const float* W_in   = (const float*)d_in[1];
  const float* b_in   = (const float*)d_in[2];
  const float* W_liq  = (const float*)d_in[3];
  const float* b_liq  = (const float*)d_in[4];
  const float* g_liq  = (const float*)d_in[5];
  const float* be_liq = (const float*)d_in[6];
  const float* W_v    = (const float*)d_in[7];
  const float* b_v    = (const float*)d_in[8];
  const float* W_o    = (const float*)d_in[9];
  const float* b_o    = (const float*)d_in[10];
  const float* g_att  = (const float*)d_in[11];
  const float* be_att = (const float*)d_in[12];
  const float* tau    = (const float*)d_in[13];
  const float* W1     = (const float*)d_in[14];
  const float* b1     = (const float*)d_in[15];
  const float* W2     = (const float*)d_in[16];
  const float* b2     = (const float*)d_in[17];
  float* out = (float*)d_out;

  u16* ws = (u16*)d_ws;
  u16* wsliq = ws;                         // 3*512*512
  u16* wsov  = ws + 786432;                // 512*512 (Wov + I)
  u16* wswin = ws + 1048576;               // 512*256
  u16* wsw1  = ws + 1179648;               // 512*1024
  u16* wsw2  = ws + 1703936;               // 128*512
  float* wsbov = (float*)(ws + 1769472);   // 512 f
  float* wsz   = (float*)(ws + 1770496);   // 512 f

  prep_convert<<<1024, 256, 0, stream>>>(W_liq, W_in, W1, W2, wsliq, wswin, wsw1, wsw2);
  prep_ov<<<512, 256, 0, stream>>>(W_v, W_o, b_v, b_o, wsov, wsbov);
  prep_z<<<1, 512, 0, stream>>>(be_liq, g_att, be_att, wsov, wsbov, wsz);

  const int SMEM = 2*RROWS*STRIDE*2 + RROWS*NW*(int)sizeof(float2) + RROWS*(int)sizeof(float2);
  hipFuncSetAttribute((const void*)liquid_main, hipFuncAttributeMaxDynamicSharedMemorySize, SMEM);
  liquid_main<<<32768/RROWS, 256, SMEM, stream>>>(
      x, b_in, b_liq, g_liq, be_liq, g_att, be_att, tau, b1, b2,
      wsliq, wsov, wsbov, wswin, wsw1, wsw2, wsz, out);
}

// Round 9
// 662.623 us; speedup vs baseline: 1.7867x; 1.7867x over previous
//
#include <hip/hip_runtime.h>
#include <hip/hip_bf16.h>

#define HH 512
#define IN_F 256
#define OUT_F 128
#define NSTEPS 3
#define NL 3
#define RROWS 64
#define STRIDE 520   // bf16 elements; 1040B pitch
#define NW 8         // 512 threads; wave grid 1 (rows) x 8 (cols); wave tile 64x64

typedef __attribute__((ext_vector_type(8))) short short8;
typedef __attribute__((ext_vector_type(4))) float f32x4;
typedef unsigned short u16;
typedef unsigned int u32;

static __device__ __forceinline__ float bf2f(u16 v){
  return __uint_as_float(((u32)v) << 16);
}
static __device__ __forceinline__ u16 f2bf(float f){   // RNE bf16
  u32 x = __float_as_uint(f);
  x += 0x7fffu + ((x >> 16) & 1u);
  return (u16)(x >> 16);
}
static __device__ __forceinline__ float fast_tanh(float x){
  float e = __expf(2.0f * x);
  return 1.0f - 2.0f / (e + 1.0f);
}
static __device__ __forceinline__ short8 ld8(const u16* p){
  return *reinterpret_cast<const short8*>(p);
}

// ---------------- prep kernels ----------------

__global__ void prep_convert(const float* __restrict__ Wliq, const float* __restrict__ Win,
                             const float* __restrict__ W1, const float* __restrict__ W2,
                             u16* __restrict__ oliq, u16* __restrict__ owin,
                             u16* __restrict__ ow1, u16* __restrict__ ow2)
{
  int tid = blockIdx.x * blockDim.x + threadIdx.x;
  int nt  = gridDim.x * blockDim.x;
  for (int i = tid; i < NL*HH*HH; i += nt){
    int rem = i % (HH*HH);
    int r = rem / HH, c = rem % HH;
    oliq[i] = f2bf(Wliq[i] + ((r == c) ? 1.0f : 0.0f));   // fold +I: pre = h@(W+I)^T + b
  }
  for (int i = tid; i < HH*IN_F;  i += nt) owin[i] = f2bf(Win[i]);
  for (int i = tid; i < HH*2*HH;  i += nt) ow1[i]  = f2bf(W1[i]);
  for (int i = tid; i < OUT_F*HH; i += nt) ow2[i]  = f2bf(W2[i]);
}

// W_ov = W_o @ W_v ; b_ov = W_o @ b_v + b_o  (single-token attention fold; NO +I)
__global__ void prep_ov(const float* __restrict__ Wv, const float* __restrict__ Wo,
                        const float* __restrict__ bv, const float* __restrict__ bo,
                        u16* __restrict__ oov, float* __restrict__ obov)
{
  __shared__ float srow[HH];
  __shared__ float rbuf[256];
  const int i = blockIdx.x;
  const int t = threadIdx.x;
  srow[t]       = Wo[i*HH + t];
  srow[t + 256] = Wo[i*HH + t + 256];
  __syncthreads();
  #pragma unroll
  for (int half = 0; half < 2; ++half){
    int j = t + half*256;
    float a0 = 0.f, a1 = 0.f;
    for (int k = 0; k < HH; k += 2){
      a0 += srow[k]   * Wv[(k)*HH + j];
      a1 += srow[k+1] * Wv[(k+1)*HH + j];
    }
    oov[i*HH + j] = f2bf(a0 + a1);
  }
  float p = 0.f;
  for (int k = t; k < HH; k += 256) p += srow[k] * bv[k];
  rbuf[t] = p; __syncthreads();
  for (int s = 128; s > 0; s >>= 1){ if (t < s) rbuf[t] += rbuf[t + s]; __syncthreads(); }
  if (t == 0) obov[i] = rbuf[0] + bo[i];
}

// Step-0 collapse: h=0 -> LN_l = beta_liq[l]; c1 = sum_l beta; v = c1@Wov^T + bov + c1;
// z = LN(v)*g_att + be_att. Then h1 = tanh(z + xin)/(tau+eps), elementwise.
__global__ void prep_z(const float* __restrict__ be_liq, const float* __restrict__ g_att,
                       const float* __restrict__ be_att, const u16* __restrict__ Wov,
                       const float* __restrict__ bov, float* __restrict__ z_out)
{
  __shared__ float c1s[HH];
  __shared__ float2 rr[HH];
  const int n = threadIdx.x;
  const float c1 = be_liq[n] + be_liq[HH + n] + be_liq[2*HH + n];
  c1s[n] = c1;
  __syncthreads();
  float a = 0.f;
  for (int k = 0; k < HH; ++k) a += c1s[k] * bf2f(Wov[(size_t)n*HH + k]);
  const float v = a + bov[n] + c1;
  rr[n] = make_float2(v, v*v);
  __syncthreads();
  for (int s = 256; s > 0; s >>= 1){
    if (n < s){ rr[n].x += rr[n+s].x; rr[n].y += rr[n+s].y; }
    __syncthreads();
  }
  const float mu = rr[0].x * (1.f/HH);
  const float va = rr[0].y * (1.f/HH) - mu*mu;
  z_out[n] = (v - mu) * rsqrtf(va + 1e-5f) * g_att[n] + be_att[n];
}

// ---------------- main fused kernel ----------------
// 8 waves (512 thr), wave grid 1x8; wave tile 64 rows x 64 cols.
// Persistent arch regs: xpk 32 + liqpk 32; acc[4][4] = MFMA C-operands (AGPR-eligible).
// B panel per gemm read once per block (no inter-wave duplication), 4x reuse per load.

#define ZERO44(A) { _Pragma("unroll") for (int _i=0;_i<4;++_i) _Pragma("unroll") for (int _j=0;_j<4;++_j) A[_i][_j] = (f32x4){0.f,0.f,0.f,0.f}; }

__device__ __forceinline__ void gemm64(const u16* ldsA, const u16* __restrict__ W,
    const int Wk, const int kSteps, const int wc, const int lr, const int lg,
    f32x4 (&acc)[4][4])
{
  const u16* pw = W + (size_t)(wc*64 + lr)*Wk + lg*8;
  const u16* pa = ldsA + lr*STRIDE + lg*8;
  for (int ks = 0; ks < kSteps; ++ks){
    short8 b0 = ld8(pw + ks*32);
    short8 b1 = ld8(pw + (size_t)16*Wk + ks*32);
    short8 b2 = ld8(pw + (size_t)32*Wk + ks*32);
    short8 b3 = ld8(pw + (size_t)48*Wk + ks*32);
    short8 a0 = ld8(pa + ks*32);
    short8 a1 = ld8(pa + 16*STRIDE + ks*32);
    short8 a2 = ld8(pa + 32*STRIDE + ks*32);
    short8 a3 = ld8(pa + 48*STRIDE + ks*32);
    acc[0][0] = __builtin_amdgcn_mfma_f32_16x16x32_bf16(a0, b0, acc[0][0], 0, 0, 0);
    acc[0][1] = __builtin_amdgcn_mfma_f32_16x16x32_bf16(a0, b1, acc[0][1], 0, 0, 0);
    acc[0][2] = __builtin_amdgcn_mfma_f32_16x16x32_bf16(a0, b2, acc[0][2], 0, 0, 0);
    acc[0][3] = __builtin_amdgcn_mfma_f32_16x16x32_bf16(a0, b3, acc[0][3], 0, 0, 0);
    acc[1][0] = __builtin_amdgcn_mfma_f32_16x16x32_bf16(a1, b0, acc[1][0], 0, 0, 0);
    acc[1][1] = __builtin_amdgcn_mfma_f32_16x16x32_bf16(a1, b1, acc[1][1], 0, 0, 0);
    acc[1][2] = __builtin_amdgcn_mfma_f32_16x16x32_bf16(a1, b2, acc[1][2], 0, 0, 0);
    acc[1][3] = __builtin_amdgcn_mfma_f32_16x16x32_bf16(a1, b3, acc[1][3], 0, 0, 0);
    acc[2][0] = __builtin_amdgcn_mfma_f32_16x16x32_bf16(a2, b0, acc[2][0], 0, 0, 0);
    acc[2][1] = __builtin_amdgcn_mfma_f32_16x16x32_bf16(a2, b1, acc[2][1], 0, 0, 0);
    acc[2][2] = __builtin_amdgcn_mfma_f32_16x16x32_bf16(a2, b2, acc[2][2], 0, 0, 0);
    acc[2][3] = __builtin_amdgcn_mfma_f32_16x16x32_bf16(a2, b3, acc[2][3], 0, 0, 0);
    acc[3][0] = __builtin_amdgcn_mfma_f32_16x16x32_bf16(a3, b0, acc[3][0], 0, 0, 0);
    acc[3][1] = __builtin_amdgcn_mfma_f32_16x16x32_bf16(a3, b1, acc[3][1], 0, 0, 0);
    acc[3][2] = __builtin_amdgcn_mfma_f32_16x16x32_bf16(a3, b2, acc[3][2], 0, 0, 0);
    acc[3][3] = __builtin_amdgcn_mfma_f32_16x16x32_bf16(a3, b3, acc[3][3], 0, 0, 0);
  }
}

// per-row LN stats over 512 cols; results land in red2[row] = (mean, rstd)
__device__ __forceinline__ void ln_rows64(const f32x4 (&v)[4][4],
    const int wc, const int lr, const int lg, const int tid,
    float2* __restrict__ red1, float2* __restrict__ red2)
{
  float s[4][4], q[4][4];
  #pragma unroll
  for (int ti = 0; ti < 4; ++ti)
    #pragma unroll
    for (int r = 0; r < 4; ++r){
      float ss = 0.f, qq = 0.f;
      #pragma unroll
      for (int tn = 0; tn < 4; ++tn){ float xv = v[ti][tn][r]; ss += xv; qq += xv*xv; }
      s[ti][r] = ss; q[ti][r] = qq;
    }
  #pragma unroll
  for (int m = 1; m < 16; m <<= 1)
    #pragma unroll
    for (int ti = 0; ti < 4; ++ti)
      #pragma unroll
      for (int r = 0; r < 4; ++r){
        s[ti][r] += __shfl_xor(s[ti][r], m, 64);
        q[ti][r] += __shfl_xor(q[ti][r], m, 64);
      }
  #pragma unroll
  for (int ti = 0; ti < 4; ++ti)
    #pragma unroll
    for (int r = 0; r < 4; ++r)
      if (lr == ti*4 + r)
        red1[(ti*16 + lg*4 + r)*NW + wc] = make_float2(s[ti][r], q[ti][r]);
  __syncthreads();
  if (tid < RROWS){
    float S = 0.f, Q = 0.f;
    #pragma unroll
    for (int w = 0; w < NW; ++w){ float2 p = red1[tid*NW + w]; S += p.x; Q += p.y; }
    float mu = S * (1.0f/HH);
    float va = Q * (1.0f/HH) - mu*mu;
    red2[tid] = make_float2(mu, rsqrtf(va + 1e-5f));
  }
  __syncthreads();
}

__global__ __launch_bounds__(512)
void liquid_main(
    const float* __restrict__ x, const float* __restrict__ b_in,
    const float* __restrict__ b_liq, const float* __restrict__ g_liq, const float* __restrict__ be_liq,
    const float* __restrict__ g_att, const float* __restrict__ be_att,
    const float* __restrict__ tau,
    const float* __restrict__ b1, const float* __restrict__ b2,
    const u16* __restrict__ Wliq_b, const u16* __restrict__ Wov_b, const float* __restrict__ bov,
    const u16* __restrict__ Win_b, const u16* __restrict__ W1_b, const u16* __restrict__ W2_b,
    const float* __restrict__ zv,
    float* __restrict__ out)
{
  extern __shared__ char smem[];
  u16* A0 = (u16*)smem;                        // h buffer (persists through each step)
  u16* L0 = A0 + RROWS*STRIDE;                 // liq / h0 operand buffer
  float2* red1 = (float2*)(L0 + RROWS*STRIDE); // [64][NW]
  float2* red2 = red1 + RROWS*NW;              // [64]

  const int tid = threadIdx.x;
  const int lane = tid & 63;
  const int wc = tid >> 6;       // wave col-group 0..7
  const int lr = lane & 15, lg = lane >> 4;
  const int rb = blockIdx.x;

  f32x4 acc[4][4];               // MFMA accumulator (AGPR-eligible)
  u32 xpk[4][4][2];              // xin packed bf16
  u32 liqpk[4][4][2];            // liq running sum packed bf16

  // ---- phase 0: stage x (bf16) into A0 cols 0..255 ----
  {
    const float4* xg = reinterpret_cast<const float4*>(x + (size_t)rb * RROWS * IN_F);
    #pragma unroll
    for (int j = 0; j < 8; ++j){
      int i4 = tid + j*512;
      float4 v = xg[i4];
      int m = i4 >> 6, c = (i4 & 63) << 2;
      u32 lo = (u32)f2bf(v.x) | ((u32)f2bf(v.y) << 16);
      u32 hi = (u32)f2bf(v.z) | ((u32)f2bf(v.w) << 16);
      *reinterpret_cast<uint2*>(A0 + m*STRIDE + c) = make_uint2(lo, hi);
    }
  }
  __syncthreads();
  ZERO44(acc);
  gemm64(A0, Win_b, IN_F, IN_F/32, wc, lr, lg, acc);
  __syncthreads();   // all x-reads of A0 done before h overwrites it

  // xin = x@Win^T + b_in (packed bf16); h1 = tanh(z + xin)*it -> A0
  #pragma unroll
  for (int tn = 0; tn < 4; ++tn){
    const int n = wc*64 + tn*16 + lr;
    const float bi = b_in[n];
    const float zn = zv[n];
    const float it = 1.0f/(tau[n] + 1e-6f);
    #pragma unroll
    for (int ti = 0; ti < 4; ++ti){
      float x0 = acc[ti][tn][0]+bi, x1 = acc[ti][tn][1]+bi;
      float x2 = acc[ti][tn][2]+bi, x3 = acc[ti][tn][3]+bi;
      xpk[ti][tn][0] = (u32)f2bf(x0) | ((u32)f2bf(x1) << 16);
      xpk[ti][tn][1] = (u32)f2bf(x2) | ((u32)f2bf(x3) << 16);
      const int mrow = ti*16 + lg*4;
      A0[(mrow + 0)*STRIDE + n] = f2bf(fast_tanh(zn + x0) * it);
      A0[(mrow + 1)*STRIDE + n] = f2bf(fast_tanh(zn + x1) * it);
      A0[(mrow + 2)*STRIDE + n] = f2bf(fast_tanh(zn + x2) * it);
      A0[(mrow + 3)*STRIDE + n] = f2bf(fast_tanh(zn + x3) * it);
    }
  }

  // ---- steps 1..2 (step 0 collapsed into z) ----
  for (int t = 0; t < NSTEPS-1; ++t){
    __syncthreads();   // h writes visible
    for (int l = 0; l < NL; ++l){
      ZERO44(acc);
      gemm64(A0, Wliq_b + (size_t)l*HH*HH, HH, HH/32, wc, lr, lg, acc);
      #pragma unroll
      for (int tn = 0; tn < 4; ++tn){
        const float bb = b_liq[l*HH + wc*64 + tn*16 + lr];
        #pragma unroll
        for (int ti = 0; ti < 4; ++ti)
          #pragma unroll
          for (int r = 0; r < 4; ++r) acc[ti][tn][r] += bb;
      }
      ln_rows64(acc, wc, lr, lg, tid, red1, red2);
      // liq running sum in packed bf16 registers
      #pragma unroll
      for (int tn = 0; tn < 4; ++tn){
        const int n = wc*64 + tn*16 + lr;
        const float gg = g_liq[l*HH + n], be = be_liq[l*HH + n];
        #pragma unroll
        for (int ti = 0; ti < 4; ++ti){
          float v0, v1, v2, v3;
          {
            const float2 st0 = red2[ti*16 + lg*4 + 0];
            const float2 st1 = red2[ti*16 + lg*4 + 1];
            const float2 st2 = red2[ti*16 + lg*4 + 2];
            const float2 st3 = red2[ti*16 + lg*4 + 3];
            v0 = (acc[ti][tn][0] - st0.x) * st0.y * gg + be;
            v1 = (acc[ti][tn][1] - st1.x) * st1.y * gg + be;
            v2 = (acc[ti][tn][2] - st2.x) * st2.y * gg + be;
            v3 = (acc[ti][tn][3] - st3.x) * st3.y * gg + be;
          }
          if (l > 0){
            v0 += bf2f((u16)(liqpk[ti][tn][0]));
            v1 += bf2f((u16)(liqpk[ti][tn][0] >> 16));
            v2 += bf2f((u16)(liqpk[ti][tn][1]));
            v3 += bf2f((u16)(liqpk[ti][tn][1] >> 16));
          }
          liqpk[ti][tn][0] = (u32)f2bf(v0) | ((u32)f2bf(v1) << 16);
          liqpk[ti][tn][1] = (u32)f2bf(v2) | ((u32)f2bf(v3) << 16);
        }
      }
    }
    // liq -> L0 (bf16) for the OV GEMM
    #pragma unroll
    for (int ti = 0; ti < 4; ++ti)
      #pragma unroll
      for (int tn = 0; tn < 4; ++tn){
        const int n = wc*64 + tn*16 + lr;
        #pragma unroll
        for (int r = 0; r < 4; ++r)
          L0[(ti*16 + lg*4 + r)*STRIDE + n] =
              (u16)(liqpk[ti][tn][r >> 1] >> ((r & 1) * 16));
      }
    __syncthreads();
    ZERO44(acc);
    gemm64(L0, Wov_b, HH, HH/32, wc, lr, lg, acc);
    // att + liq (+bov); residual from packed regs
    #pragma unroll
    for (int tn = 0; tn < 4; ++tn){
      const float bo_ = bov[wc*64 + tn*16 + lr];
      #pragma unroll
      for (int ti = 0; ti < 4; ++ti)
        #pragma unroll
        for (int r = 0; r < 4; ++r)
          acc[ti][tn][r] += bo_ + bf2f((u16)(liqpk[ti][tn][r >> 1] >> ((r & 1) * 16)));
    }
    ln_rows64(acc, wc, lr, lg, tid, red1, red2);
    // h update in place in A0
    #pragma unroll
    for (int tn = 0; tn < 4; ++tn){
      const int n = wc*64 + tn*16 + lr;
      const float ga = g_att[n], ba = be_att[n];
      const float it = 1.0f/(tau[n] + 1e-6f);
      #pragma unroll
      for (int ti = 0; ti < 4; ++ti)
        #pragma unroll
        for (int r = 0; r < 4; ++r){
          const int m = ti*16 + lg*4 + r;
          const float2 st = red2[m];
          const float l2 = (acc[ti][tn][r] - st.x) * st.y * ga + ba;
          const float xi = bf2f((u16)(xpk[ti][tn][r >> 1] >> ((r & 1) * 16)));
          const float ho = bf2f(A0[m*STRIDE + n]);
          A0[m*STRIDE + n] = f2bf(ho + (fast_tanh(l2 + xi) - ho) * it);
        }
    }
  }

  // ---- head: h0 = tanh(z+xin)*it -> L0 (recomputed from xpk) ----
  __syncthreads();
  #pragma unroll
  for (int tn = 0; tn < 4; ++tn){
    const int n = wc*64 + tn*16 + lr;
    const float zn = zv[n];
    const float it = 1.0f/(tau[n] + 1e-6f);
    #pragma unroll
    for (int ti = 0; ti < 4; ++ti)
      #pragma unroll
      for (int r = 0; r < 4; ++r){
        const float xi = bf2f((u16)(xpk[ti][tn][r >> 1] >> ((r & 1) * 16)));
        L0[(ti*16 + lg*4 + r)*STRIDE + n] = f2bf(fast_tanh(zn + xi) * it);
      }
  }
  __syncthreads();
  ZERO44(acc);
  gemm64(A0, W1_b,      2*HH, HH/32, wc, lr, lg, acc);  // h part (k 0..511)
  gemm64(L0, W1_b + HH, 2*HH, HH/32, wc, lr, lg, acc);  // h0 part (k 512..1023)
  #pragma unroll
  for (int tn = 0; tn < 4; ++tn){
    const float bb = b1[wc*64 + tn*16 + lr];
    #pragma unroll
    for (int ti = 0; ti < 4; ++ti)
      #pragma unroll
      for (int r = 0; r < 4; ++r)
        acc[ti][tn][r] = fmaxf(acc[ti][tn][r] + bb, 0.f);
  }
  __syncthreads();   // W1 gemm reads of A0/L0 done before overwrite
  #pragma unroll
  for (int ti = 0; ti < 4; ++ti)
    #pragma unroll
    for (int tn = 0; tn < 4; ++tn){
      const int n = wc*64 + tn*16 + lr;
      #pragma unroll
      for (int r = 0; r < 4; ++r)
        A0[(ti*16 + lg*4 + r)*STRIDE + n] = f2bf(acc[ti][tn][r]);
    }
  __syncthreads();

  // final [64,512] @ W2^T -> [64,128]; 8 waves: 64 rows x 16 cols per wave
  {
    f32x4 a2[4];
    #pragma unroll
    for (int ti = 0; ti < 4; ++ti) a2[ti] = (f32x4){0.f,0.f,0.f,0.f};
    const u16* pw2 = W2_b + (size_t)(wc*16 + lr)*HH + lg*8;
    const u16* pa2 = A0 + lr*STRIDE + lg*8;
    for (int ks = 0; ks < HH/32; ++ks){
      short8 bb2 = ld8(pw2 + ks*32);
      #pragma unroll
      for (int ti = 0; ti < 4; ++ti){
        short8 aa = ld8(pa2 + ti*16*STRIDE + ks*32);
        a2[ti] = __builtin_amdgcn_mfma_f32_16x16x32_bf16(aa, bb2, a2[ti], 0, 0, 0);
      }
    }
    const int n = wc*16 + lr;
    const float bb = b2[n];
    #pragma unroll
    for (int ti = 0; ti < 4; ++ti)
      #pragma unroll
      for (int r = 0; r < 4; ++r){
        const int m = ti*16 + lg*4 + r;
        out[(size_t)(rb*RROWS + m)*OUT_F + n] = a2[ti][r] + bb;
      }
  }
}

// ---------------- launch ----------------

extern "C" void kernel_launch(void* const* d_in, const int* in_sizes, int n_in,
                              void* d_out, int out_size, void* d_ws, size_t ws_size,
                              hipStream_t stream)
{
  (void)in_sizes; (void)n_in; (void)out_size; (void)ws_size;
  const float* x      = (const float*)d_in[0];
  const float* W_in   = (const float*)d_in[1];
  const float* b_in   = (const float*)d_in[2];
  const float* W_liq  = (const float*)d_in[3];
  const float* b_liq  = (const float*)d_in[4];
  const float* g_liq  = (const float*)d_in[5];
  const float* be_liq = (const float*)d_in[6];
  const float* W_v    = (const float*)d_in[7];
  const float* b_v    = (const float*)d_in[8];
  const float* W_o    = (const float*)d_in[9];
  const float* b_o    = (const float*)d_in[10];
  const float* g_att  = (const float*)d_in[11];
  const float* be_att = (const float*)d_in[12];
  const float* tau    = (const float*)d_in[13];
  const float* W1     = (const float*)d_in[14];
  const float* b1     = (const float*)d_in[15];
  const float* W2     = (const float*)d_in[16];
  const float* b2     = (const float*)d_in[17];
  float* out = (float*)d_out;

  u16* ws = (u16*)d_ws;
  u16* wsliq = ws;                         // 3*512*512
  u16* wsov  = ws + 786432;                // 512*512
  u16* wswin = ws + 1048576;               // 512*256
  u16* wsw1  = ws + 1179648;               // 512*1024
  u16* wsw2  = ws + 1703936;               // 128*512
  float* wsbov = (float*)(ws + 1769472);   // 512 f
  float* wsz   = (float*)(ws + 1770496);   // 512 f

  prep_convert<<<1024, 256, 0, stream>>>(W_liq, W_in, W1, W2, wsliq, wswin, wsw1, wsw2);
  prep_ov<<<512, 256, 0, stream>>>(W_v, W_o, b_v, b_o, wsov, wsbov);
  prep_z<<<1, 512, 0, stream>>>(be_liq, g_att, be_att, wsov, wsbov, wsz);

  const int SMEM = 2*RROWS*STRIDE*2 + RROWS*NW*(int)sizeof(float2) + RROWS*(int)sizeof(float2);
  hipFuncSetAttribute((const void*)liquid_main, hipFuncAttributeMaxDynamicSharedMemorySize, SMEM);
  liquid_main<<<32768/RROWS, 512, SMEM, stream>>>(
      x, b_in, b_liq, g_liq, be_liq, g_att, be_att, tau, b1, b2,
      wsliq, wsov, wsbov, wswin, wsw1, wsw2, wsz, out);
}

// Round 10
// 643.455 us; speedup vs baseline: 1.8399x; 1.0298x over previous
//
#include <hip/hip_runtime.h>
#include <hip/hip_bf16.h>

#define HH 512
#define IN_F 256
#define OUT_F 128
#define NSTEPS 3
#define NL 3
#define RROWS 64
#define STRIDE 520   // bf16 elements; 1040B pitch
#define NW 8         // 512 threads; wave grid 1 (rows) x 8 (cols); wave tile 64x64

typedef __attribute__((ext_vector_type(8))) short short8;
typedef __attribute__((ext_vector_type(4))) float f32x4;
typedef unsigned short u16;
typedef unsigned int u32;

static __device__ __forceinline__ float bf2f(u16 v){
  return __uint_as_float(((u32)v) << 16);
}
static __device__ __forceinline__ u16 f2bf(float f){   // RNE bf16
  u32 x = __float_as_uint(f);
  x += 0x7fffu + ((x >> 16) & 1u);
  return (u16)(x >> 16);
}
static __device__ __forceinline__ float fast_tanh(float x){
  float e = __expf(2.0f * x);
  return 1.0f - 2.0f / (e + 1.0f);
}
static __device__ __forceinline__ short8 ld8(const u16* p){
  return *reinterpret_cast<const short8*>(p);
}

// ---------------- prep kernels ----------------

__global__ void prep_convert(const float* __restrict__ Wliq, const float* __restrict__ Win,
                             const float* __restrict__ W1, const float* __restrict__ W2,
                             u16* __restrict__ oliq, u16* __restrict__ owin,
                             u16* __restrict__ ow1, u16* __restrict__ ow2)
{
  int tid = blockIdx.x * blockDim.x + threadIdx.x;
  int nt  = gridDim.x * blockDim.x;
  for (int i = tid; i < NL*HH*HH; i += nt){
    int rem = i % (HH*HH);
    int r = rem / HH, c = rem % HH;
    oliq[i] = f2bf(Wliq[i] + ((r == c) ? 1.0f : 0.0f));   // fold +I: pre = h@(W+I)^T + b
  }
  for (int i = tid; i < HH*IN_F;  i += nt) owin[i] = f2bf(Win[i]);
  for (int i = tid; i < HH*2*HH;  i += nt) ow1[i]  = f2bf(W1[i]);
  for (int i = tid; i < OUT_F*HH; i += nt) ow2[i]  = f2bf(W2[i]);
}

// W_ov = W_o @ W_v ; b_ov = W_o @ b_v + b_o  (single-token attention fold)
__global__ void prep_ov(const float* __restrict__ Wv, const float* __restrict__ Wo,
                        const float* __restrict__ bv, const float* __restrict__ bo,
                        u16* __restrict__ oov, float* __restrict__ obov)
{
  __shared__ float srow[HH];
  __shared__ float rbuf[256];
  const int i = blockIdx.x;
  const int t = threadIdx.x;
  srow[t]       = Wo[i*HH + t];
  srow[t + 256] = Wo[i*HH + t + 256];
  __syncthreads();
  #pragma unroll
  for (int half = 0; half < 2; ++half){
    int j = t + half*256;
    float a0 = 0.f, a1 = 0.f;
    for (int k = 0; k < HH; k += 2){
      a0 += srow[k]   * Wv[(k)*HH + j];
      a1 += srow[k+1] * Wv[(k+1)*HH + j];
    }
    oov[i*HH + j] = f2bf(a0 + a1);
  }
  float p = 0.f;
  for (int k = t; k < HH; k += 256) p += srow[k] * bv[k];
  rbuf[t] = p; __syncthreads();
  for (int s = 128; s > 0; s >>= 1){ if (t < s) rbuf[t] += rbuf[t + s]; __syncthreads(); }
  if (t == 0) obov[i] = rbuf[0] + bo[i];
}

// Step-0 collapse: h=0 -> LN_l = beta_liq[l]; c1 = sum_l beta; v = c1@Wov^T + bov + c1;
// z = LN(v)*g_att + be_att. Then h1 = tanh(z + xin)/(tau+eps), elementwise.
__global__ void prep_z(const float* __restrict__ be_liq, const float* __restrict__ g_att,
                       const float* __restrict__ be_att, const u16* __restrict__ Wov,
                       const float* __restrict__ bov, float* __restrict__ z_out)
{
  __shared__ float c1s[HH];
  __shared__ float2 rr[HH];
  const int n = threadIdx.x;
  const float c1 = be_liq[n] + be_liq[HH + n] + be_liq[2*HH + n];
  c1s[n] = c1;
  __syncthreads();
  float a = 0.f;
  for (int k = 0; k < HH; ++k) a += c1s[k] * bf2f(Wov[(size_t)n*HH + k]);
  const float v = a + bov[n] + c1;
  rr[n] = make_float2(v, v*v);
  __syncthreads();
  for (int s = 256; s > 0; s >>= 1){
    if (n < s){ rr[n].x += rr[n+s].x; rr[n].y += rr[n+s].y; }
    __syncthreads();
  }
  const float mu = rr[0].x * (1.f/HH);
  const float va = rr[0].y * (1.f/HH) - mu*mu;
  z_out[n] = (v - mu) * rsqrtf(va + 1e-5f) * g_att[n] + be_att[n];
}

// ---------------- main fused kernel ----------------
// 8 waves (512 thr), wave grid 1x8; wave tile 64 rows x 64 cols.
// Register diet: acc[4][4] is the ONLY persistent array (MFMA C-operands).
// xin lives in d_ws (bf16-packed u32, lane-interleaved -> coalesced); liq
// accumulates in L0 via bf16 RMW; h lives in A0. Peak live ~120 <= 128 cap.

#define ZERO44(A) { _Pragma("unroll") for (int _i=0;_i<4;++_i) _Pragma("unroll") for (int _j=0;_j<4;++_j) A[_i][_j] = (f32x4){0.f,0.f,0.f,0.f}; }

__device__ __forceinline__ void gemm64(const u16* ldsA, const u16* __restrict__ W,
    const int Wk, const int kSteps, const int wc, const int lr, const int lg,
    f32x4 (&acc)[4][4])
{
  const u16* pw = W + (size_t)(wc*64 + lr)*Wk + lg*8;
  const u16* pa = ldsA + lr*STRIDE + lg*8;
  for (int ks = 0; ks < kSteps; ++ks){
    short8 b0 = ld8(pw + ks*32);
    short8 b1 = ld8(pw + (size_t)16*Wk + ks*32);
    short8 b2 = ld8(pw + (size_t)32*Wk + ks*32);
    short8 b3 = ld8(pw + (size_t)48*Wk + ks*32);
    short8 a0 = ld8(pa + ks*32);
    short8 a1 = ld8(pa + 16*STRIDE + ks*32);
    short8 a2 = ld8(pa + 32*STRIDE + ks*32);
    short8 a3 = ld8(pa + 48*STRIDE + ks*32);
    acc[0][0] = __builtin_amdgcn_mfma_f32_16x16x32_bf16(a0, b0, acc[0][0], 0, 0, 0);
    acc[0][1] = __builtin_amdgcn_mfma_f32_16x16x32_bf16(a0, b1, acc[0][1], 0, 0, 0);
    acc[0][2] = __builtin_amdgcn_mfma_f32_16x16x32_bf16(a0, b2, acc[0][2], 0, 0, 0);
    acc[0][3] = __builtin_amdgcn_mfma_f32_16x16x32_bf16(a0, b3, acc[0][3], 0, 0, 0);
    acc[1][0] = __builtin_amdgcn_mfma_f32_16x16x32_bf16(a1, b0, acc[1][0], 0, 0, 0);
    acc[1][1] = __builtin_amdgcn_mfma_f32_16x16x32_bf16(a1, b1, acc[1][1], 0, 0, 0);
    acc[1][2] = __builtin_amdgcn_mfma_f32_16x16x32_bf16(a1, b2, acc[1][2], 0, 0, 0);
    acc[1][3] = __builtin_amdgcn_mfma_f32_16x16x32_bf16(a1, b3, acc[1][3], 0, 0, 0);
    acc[2][0] = __builtin_amdgcn_mfma_f32_16x16x32_bf16(a2, b0, acc[2][0], 0, 0, 0);
    acc[2][1] = __builtin_amdgcn_mfma_f32_16x16x32_bf16(a2, b1, acc[2][1], 0, 0, 0);
    acc[2][2] = __builtin_amdgcn_mfma_f32_16x16x32_bf16(a2, b2, acc[2][2], 0, 0, 0);
    acc[2][3] = __builtin_amdgcn_mfma_f32_16x16x32_bf16(a2, b3, acc[2][3], 0, 0, 0);
    acc[3][0] = __builtin_amdgcn_mfma_f32_16x16x32_bf16(a3, b0, acc[3][0], 0, 0, 0);
    acc[3][1] = __builtin_amdgcn_mfma_f32_16x16x32_bf16(a3, b1, acc[3][1], 0, 0, 0);
    acc[3][2] = __builtin_amdgcn_mfma_f32_16x16x32_bf16(a3, b2, acc[3][2], 0, 0, 0);
    acc[3][3] = __builtin_amdgcn_mfma_f32_16x16x32_bf16(a3, b3, acc[3][3], 0, 0, 0);
  }
}

// per-row LN stats over 512 cols; results land in red2[row] = (mean, rstd)
__device__ __forceinline__ void ln_rows64(const f32x4 (&v)[4][4],
    const int wc, const int lr, const int lg, const int tid,
    float2* __restrict__ red1, float2* __restrict__ red2)
{
  float s[4][4], q[4][4];
  #pragma unroll
  for (int ti = 0; ti < 4; ++ti)
    #pragma unroll
    for (int r = 0; r < 4; ++r){
      float ss = 0.f, qq = 0.f;
      #pragma unroll
      for (int tn = 0; tn < 4; ++tn){ float xv = v[ti][tn][r]; ss += xv; qq += xv*xv; }
      s[ti][r] = ss; q[ti][r] = qq;
    }
  #pragma unroll
  for (int m = 1; m < 16; m <<= 1)
    #pragma unroll
    for (int ti = 0; ti < 4; ++ti)
      #pragma unroll
      for (int r = 0; r < 4; ++r){
        s[ti][r] += __shfl_xor(s[ti][r], m, 64);
        q[ti][r] += __shfl_xor(q[ti][r], m, 64);
      }
  #pragma unroll
  for (int ti = 0; ti < 4; ++ti)
    #pragma unroll
    for (int r = 0; r < 4; ++r)
      if (lr == ti*4 + r)
        red1[(ti*16 + lg*4 + r)*NW + wc] = make_float2(s[ti][r], q[ti][r]);
  __syncthreads();
  if (tid < RROWS){
    float S = 0.f, Q = 0.f;
    #pragma unroll
    for (int w = 0; w < NW; ++w){ float2 p = red1[tid*NW + w]; S += p.x; Q += p.y; }
    float mu = S * (1.0f/HH);
    float va = Q * (1.0f/HH) - mu*mu;
    red2[tid] = make_float2(mu, rsqrtf(va + 1e-5f));
  }
  __syncthreads();
}

__global__ __launch_bounds__(512)
void liquid_main(
    const float* __restrict__ x, const float* __restrict__ b_in,
    const float* __restrict__ b_liq, const float* __restrict__ g_liq, const float* __restrict__ be_liq,
    const float* __restrict__ g_att, const float* __restrict__ be_att,
    const float* __restrict__ tau,
    const float* __restrict__ b1, const float* __restrict__ b2,
    const u16* __restrict__ Wliq_b, const u16* __restrict__ Wov_b, const float* __restrict__ bov,
    const u16* __restrict__ Win_b, const u16* __restrict__ W1_b, const u16* __restrict__ W2_b,
    const float* __restrict__ zv,
    u32* __restrict__ xin_ws,   // [grid][32][512] u32: j*512 + tid, per-block base rb*16384
    float* __restrict__ out)
{
  extern __shared__ char smem[];
  u16* A0 = (u16*)smem;                        // h buffer (persists through each step)
  u16* L0 = A0 + RROWS*STRIDE;                 // liq accumulation / h0 operand buffer
  float2* red1 = (float2*)(L0 + RROWS*STRIDE); // [64][NW]
  float2* red2 = red1 + RROWS*NW;              // [64]

  const int tid = threadIdx.x;
  const int lane = tid & 63;
  const int wc = tid >> 6;       // wave col-group 0..7
  const int lr = lane & 15, lg = lane >> 4;
  const int rb = blockIdx.x;
  const int xb = rb * 16384;     // per-block xin base (u32 index)

  f32x4 acc[4][4];               // the ONLY persistent register array

  // ---- phase 0: stage x (bf16) into A0 cols 0..255 ----
  {
    const float4* xg = reinterpret_cast<const float4*>(x + (size_t)rb * RROWS * IN_F);
    #pragma unroll
    for (int j = 0; j < 8; ++j){
      int i4 = tid + j*512;
      float4 v = xg[i4];
      int m = i4 >> 6, c = (i4 & 63) << 2;
      u32 lo = (u32)f2bf(v.x) | ((u32)f2bf(v.y) << 16);
      u32 hi = (u32)f2bf(v.z) | ((u32)f2bf(v.w) << 16);
      *reinterpret_cast<uint2*>(A0 + m*STRIDE + c) = make_uint2(lo, hi);
    }
  }
  __syncthreads();
  ZERO44(acc);
  gemm64(A0, Win_b, IN_F, IN_F/32, wc, lr, lg, acc);
  __syncthreads();   // all x-reads of A0 done before h overwrites it

  // xin = x@Win^T + b_in -> packed bf16 to ws (coalesced); h1 = tanh(z+xin)*it -> A0
  #pragma unroll
  for (int tn = 0; tn < 4; ++tn){
    const int n = wc*64 + tn*16 + lr;
    const float bi = b_in[n];
    const float zn = zv[n];
    const float it = 1.0f/(tau[n] + 1e-6f);
    #pragma unroll
    for (int ti = 0; ti < 4; ++ti){
      float x0 = acc[ti][tn][0]+bi, x1 = acc[ti][tn][1]+bi;
      float x2 = acc[ti][tn][2]+bi, x3 = acc[ti][tn][3]+bi;
      xin_ws[xb + (ti*8 + tn*2 + 0)*512 + tid] = (u32)f2bf(x0) | ((u32)f2bf(x1) << 16);
      xin_ws[xb + (ti*8 + tn*2 + 1)*512 + tid] = (u32)f2bf(x2) | ((u32)f2bf(x3) << 16);
      const int mrow = ti*16 + lg*4;
      A0[(mrow + 0)*STRIDE + n] = f2bf(fast_tanh(zn + x0) * it);
      A0[(mrow + 1)*STRIDE + n] = f2bf(fast_tanh(zn + x1) * it);
      A0[(mrow + 2)*STRIDE + n] = f2bf(fast_tanh(zn + x2) * it);
      A0[(mrow + 3)*STRIDE + n] = f2bf(fast_tanh(zn + x3) * it);
    }
  }

  // ---- steps 1..2 (step 0 collapsed into z) ----
  for (int t = 0; t < NSTEPS-1; ++t){
    __syncthreads();   // h writes visible
    for (int l = 0; l < NL; ++l){
      ZERO44(acc);
      gemm64(A0, Wliq_b + (size_t)l*HH*HH, HH, HH/32, wc, lr, lg, acc);
      #pragma unroll
      for (int tn = 0; tn < 4; ++tn){
        const float bb = b_liq[l*HH + wc*64 + tn*16 + lr];
        #pragma unroll
        for (int ti = 0; ti < 4; ++ti)
          #pragma unroll
          for (int r = 0; r < 4; ++r) acc[ti][tn][r] += bb;
      }
      ln_rows64(acc, wc, lr, lg, tid, red1, red2);
      // liq accumulation in L0 (bf16 RMW; owner-exclusive, race-free)
      #pragma unroll
      for (int tn = 0; tn < 4; ++tn){
        const int n = wc*64 + tn*16 + lr;
        const float gg = g_liq[l*HH + n], be = be_liq[l*HH + n];
        #pragma unroll
        for (int ti = 0; ti < 4; ++ti)
          #pragma unroll
          for (int r = 0; r < 4; ++r){
            const int m = ti*16 + lg*4 + r;
            const float2 st = red2[m];
            float v = (acc[ti][tn][r] - st.x) * st.y * gg + be;
            if (l > 0) v += bf2f(L0[m*STRIDE + n]);
            L0[m*STRIDE + n] = f2bf(v);
          }
      }
      // no extra sync: next GEMM reads only A0; ln_rows' barriers fence red1/red2
    }
    __syncthreads();   // L0 (liq) complete across all waves
    ZERO44(acc);
    gemm64(L0, Wov_b, HH, HH/32, wc, lr, lg, acc);
    // att + liq (+bov); residual re-read from L0
    #pragma unroll
    for (int tn = 0; tn < 4; ++tn){
      const int n = wc*64 + tn*16 + lr;
      const float bo_ = bov[n];
      #pragma unroll
      for (int ti = 0; ti < 4; ++ti)
        #pragma unroll
        for (int r = 0; r < 4; ++r)
          acc[ti][tn][r] += bo_ + bf2f(L0[(ti*16 + lg*4 + r)*STRIDE + n]);
    }
    ln_rows64(acc, wc, lr, lg, tid, red1, red2);
    // h update in place in A0; xin re-read from ws (coalesced dwords)
    #pragma unroll
    for (int tn = 0; tn < 4; ++tn){
      const int n = wc*64 + tn*16 + lr;
      const float ga = g_att[n], ba = be_att[n];
      const float it = 1.0f/(tau[n] + 1e-6f);
      #pragma unroll
      for (int ti = 0; ti < 4; ++ti){
        const u32 w0 = xin_ws[xb + (ti*8 + tn*2 + 0)*512 + tid];
        const u32 w1 = xin_ws[xb + (ti*8 + tn*2 + 1)*512 + tid];
        #pragma unroll
        for (int r = 0; r < 4; ++r){
          const int m = ti*16 + lg*4 + r;
          const float2 st = red2[m];
          const float l2 = (acc[ti][tn][r] - st.x) * st.y * ga + ba;
          const float xi = bf2f((u16)(((r & 2) ? w1 : w0) >> ((r & 1) * 16)));
          const float ho = bf2f(A0[m*STRIDE + n]);
          A0[m*STRIDE + n] = f2bf(ho + (fast_tanh(l2 + xi) - ho) * it);
        }
      }
    }
  }

  // ---- head: h0 = tanh(z+xin)*it -> L0 (xin from ws) ----
  __syncthreads();
  #pragma unroll
  for (int tn = 0; tn < 4; ++tn){
    const int n = wc*64 + tn*16 + lr;
    const float zn = zv[n];
    const float it = 1.0f/(tau[n] + 1e-6f);
    #pragma unroll
    for (int ti = 0; ti < 4; ++ti){
      const u32 w0 = xin_ws[xb + (ti*8 + tn*2 + 0)*512 + tid];
      const u32 w1 = xin_ws[xb + (ti*8 + tn*2 + 1)*512 + tid];
      #pragma unroll
      for (int r = 0; r < 4; ++r){
        const float xi = bf2f((u16)(((r & 2) ? w1 : w0) >> ((r & 1) * 16)));
        L0[(ti*16 + lg*4 + r)*STRIDE + n] = f2bf(fast_tanh(zn + xi) * it);
      }
    }
  }
  __syncthreads();   // h (A0) + h0 (L0) ready
  ZERO44(acc);
  gemm64(A0, W1_b,      2*HH, HH/32, wc, lr, lg, acc);  // h part (k 0..511)
  gemm64(L0, W1_b + HH, 2*HH, HH/32, wc, lr, lg, acc);  // h0 part (k 512..1023)
  #pragma unroll
  for (int tn = 0; tn < 4; ++tn){
    const float bb = b1[wc*64 + tn*16 + lr];
    #pragma unroll
    for (int ti = 0; ti < 4; ++ti)
      #pragma unroll
      for (int r = 0; r < 4; ++r)
        acc[ti][tn][r] = fmaxf(acc[ti][tn][r] + bb, 0.f);
  }
  __syncthreads();   // W1 gemm reads of A0/L0 done before overwrite
  #pragma unroll
  for (int ti = 0; ti < 4; ++ti)
    #pragma unroll
    for (int tn = 0; tn < 4; ++tn){
      const int n = wc*64 + tn*16 + lr;
      #pragma unroll
      for (int r = 0; r < 4; ++r)
        A0[(ti*16 + lg*4 + r)*STRIDE + n] = f2bf(acc[ti][tn][r]);
    }
  __syncthreads();

  // final [64,512] @ W2^T -> [64,128]; 8 waves: 64 rows x 16 cols per wave
  {
    f32x4 a2[4];
    #pragma unroll
    for (int ti = 0; ti < 4; ++ti) a2[ti] = (f32x4){0.f,0.f,0.f,0.f};
    const u16* pw2 = W2_b + (size_t)(wc*16 + lr)*HH + lg*8;
    const u16* pa2 = A0 + lr*STRIDE + lg*8;
    for (int ks = 0; ks < HH/32; ++ks){
      short8 bb2 = ld8(pw2 + ks*32);
      #pragma unroll
      for (int ti = 0; ti < 4; ++ti){
        short8 aa = ld8(pa2 + ti*16*STRIDE + ks*32);
        a2[ti] = __builtin_amdgcn_mfma_f32_16x16x32_bf16(aa, bb2, a2[ti], 0, 0, 0);
      }
    }
    const int n = wc*16 + lr;
    const float bb = b2[n];
    #pragma unroll
    for (int ti = 0; ti < 4; ++ti)
      #pragma unroll
      for (int r = 0; r < 4; ++r){
        const int m = ti*16 + lg*4 + r;
        out[(size_t)(rb*RROWS + m)*OUT_F + n] = a2[ti][r] + bb;
      }
  }
}

// ---------------- launch ----------------

extern "C" void kernel_launch(void* const* d_in, const int* in_sizes, int n_in,
                              void* d_out, int out_size, void* d_ws, size_t ws_size,
                              hipStream_t stream)
{
  (void)in_sizes; (void)n_in; (void)out_size; (void)ws_size;
  const float* x      = (const float*)d_in[0];
  const float* W_in   = (const float*)d_in[1];
  const float* b_in   = (const float*)d_in[2];
  const float* W_liq  = (const float*)d_in[3];
  const float* b_liq  = (const float*)d_in[4];
  const float* g_liq  = (const float*)d_in[5];
  const float* be_liq = (const float*)d_in[6];
  const float* W_v    = (const float*)d_in[7];
  const float* b_v    = (const float*)d_in[8];
  const float* W_o    = (const float*)d_in[9];
  const float* b_o    = (const float*)d_in[10];
  const float* g_att  = (const float*)d_in[11];
  const float* be_att = (const float*)d_in[12];
  const float* tau    = (const float*)d_in[13];
  const float* W1     = (const float*)d_in[14];
  const float* b1     = (const float*)d_in[15];
  const float* W2     = (const float*)d_in[16];
  const float* b2     = (const float*)d_in[17];
  float* out = (float*)d_out;

  u16* ws = (u16*)d_ws;
  u16* wsliq = ws;                         // 3*512*512
  u16* wsov  = ws + 786432;                // 512*512
  u16* wswin = ws + 1048576;               // 512*256
  u16* wsw1  = ws + 1179648;               // 512*1024
  u16* wsw2  = ws + 1703936;               // 128*512
  float* wsbov = (float*)(ws + 1769472);   // 512 f
  float* wsz   = (float*)(ws + 1770496);   // 512 f
  u32* wsxin   = (u32*)(ws + 1772032);     // 32768*512 bf16 packed = 33.5MB

  prep_convert<<<1024, 256, 0, stream>>>(W_liq, W_in, W1, W2, wsliq, wswin, wsw1, wsw2);
  prep_ov<<<512, 256, 0, stream>>>(W_v, W_o, b_v, b_o, wsov, wsbov);
  prep_z<<<1, 512, 0, stream>>>(be_liq, g_att, be_att, wsov, wsbov, wsz);

  const int SMEM = 2*RROWS*STRIDE*2 + RROWS*NW*(int)sizeof(float2) + RROWS*(int)sizeof(float2);
  hipFuncSetAttribute((const void*)liquid_main, hipFuncAttributeMaxDynamicSharedMemorySize, SMEM);
  liquid_main<<<32768/RROWS, 512, SMEM, stream>>>(
      x, b_in, b_liq, g_liq, be_liq, g_att, be_att, tau, b1, b2,
      wsliq, wsov, wsbov, wswin, wsw1, wsw2, wsz, wsxin, out);
}